// Round 1
// baseline (1300.013 us; speedup 1.0000x reference)
//
#include <hip/hip_runtime.h>

#define DEV __device__ __forceinline__

typedef __bf16 bf16x8 __attribute__((ext_vector_type(8)));
typedef float f32x4 __attribute__((ext_vector_type(4)));

DEV float bflo(unsigned int u) { union { unsigned int x; float f; } c; c.x = u << 16; return c.f; }
DEV float bfhi(unsigned int u) { union { unsigned int x; float f; } c; c.x = u & 0xffff0000u; return c.f; }
DEV unsigned short f2bf(float f) {
  union { float f; unsigned int u; } c; c.f = f;
  unsigned int u = c.u;
  return (unsigned short)((u + 0x7fffu + ((u >> 16) & 1u)) >> 16);
}

// ---------------- weight convert + zero-pad (rows appended) ----------------
__global__ __launch_bounds__(256) void wconv_kernel(const float* __restrict__ src,
                                                    unsigned short* __restrict__ dst,
                                                    int real_elems, int pad_elems) {
  int i = blockIdx.x * 256 + threadIdx.x;
  if (i < pad_elems) dst[i] = (i < real_elems) ? f2bf(src[i]) : (unsigned short)0;
}

// ---------------- LayerNorm (C=192), optional roll+window gather ----------------
template <bool GATHER>
__global__ __launch_bounds__(256) void ln_kernel(const float* __restrict__ x,
                                                 const float* __restrict__ g,
                                                 const float* __restrict__ b,
                                                 unsigned short* __restrict__ out) {
  int row = (blockIdx.x << 2) + (threadIdx.x >> 6);
  int lane = threadIdx.x & 63;
  const float* xr;
  if (GATHER) {
    int w_ = row / 343, n_ = row - w_ * 343;
    int bb = w_ >> 6, wrem = w_ & 63;
    int wd = wrem >> 4, wh = (wrem >> 2) & 3, ww = wrem & 3;
    int ii = n_ / 49, rem = n_ - ii * 49;
    int jj = rem / 7, kk = rem - jj * 7;
    int d = wd * 7 + ii + 3; if (d >= 28) d -= 28;
    int hh = wh * 7 + jj + 3; if (hh >= 28) hh -= 28;
    int wb = ww * 7 + kk + 3; if (wb >= 28) wb -= 28;
    xr = x + ((size_t)bb * 21952 + (d * 28 + hh) * 28 + wb) * 192;
  } else {
    xr = x + (size_t)row * 192;
  }
  float v0 = xr[lane], v1 = xr[lane + 64], v2 = xr[lane + 128];
  float s = v0 + v1 + v2;
  float sq = v0 * v0 + v1 * v1 + v2 * v2;
#pragma unroll
  for (int o = 32; o > 0; o >>= 1) {
    s += __shfl_xor(s, o, 64);
    sq += __shfl_xor(sq, o, 64);
  }
  float mean = s * (1.0f / 192.0f);
  float var = sq * (1.0f / 192.0f) - mean * mean;
  float rstd = rsqrtf(var + 1e-5f);
  unsigned short* orow = out + (size_t)row * 192;
  orow[lane]       = f2bf((v0 - mean) * rstd * g[lane] + b[lane]);
  orow[lane + 64]  = f2bf((v1 - mean) * rstd * g[lane + 64] + b[lane + 64]);
  orow[lane + 128] = f2bf((v2 - mean) * rstd * g[lane + 128] + b[lane + 128]);
}

// ---------------- 128x128x64 bf16 MFMA GEMM, fused epilogues ----------------
// C[M][Npad] = A[M][K] @ W[Npad][K]^T ; EPI: 0=QKV scatter, 1=proj+reverse+roll+resid,
// 2=FC1+GELU->bf16, 3=FC2+resid->f32
template <int EPI>
__global__ __launch_bounds__(256) void gemm128(
    const unsigned short* __restrict__ A, const unsigned short* __restrict__ W,
    const float* __restrict__ bias, int K,
    unsigned short* __restrict__ oq, unsigned short* __restrict__ okk,
    unsigned short* __restrict__ ov, unsigned short* __restrict__ obf,
    float* __restrict__ of, const float* __restrict__ resid) {
  __shared__ __align__(16) unsigned short As[128 * 64];
  __shared__ __align__(16) unsigned short Bs[128 * 64];
  const int tid = threadIdx.x;
  const int lane = tid & 63;
  const int wv = tid >> 6;
  const int wr = wv >> 1, wc = wv & 1;
  const int bm = blockIdx.y << 7;
  const int bn = blockIdx.x << 7;
  const int l15 = lane & 15, l4 = lane >> 4;

  f32x4 acc[4][4];
#pragma unroll
  for (int a = 0; a < 4; a++)
#pragma unroll
    for (int b2 = 0; b2 < 4; b2++) acc[a][b2] = (f32x4){0.f, 0.f, 0.f, 0.f};

  const int kiters = K >> 6;
  for (int kt = 0; kt < kiters; kt++) {
    __syncthreads();
#pragma unroll
    for (int s = 0; s < 4; s++) {
      int qq = tid + (s << 8);
      int r = qq >> 3, cc2 = qq & 7;
      uint4 av = *(const uint4*)(A + (size_t)(bm + r) * K + (kt << 6) + (cc2 << 3));
      uint4 wvv = *(const uint4*)(W + (size_t)(bn + r) * K + (kt << 6) + (cc2 << 3));
      int so = (r << 6) + ((cc2 ^ (r & 7)) << 3);
      *(uint4*)(As + so) = av;
      *(uint4*)(Bs + so) = wvv;
    }
    __syncthreads();
#pragma unroll
    for (int ks = 0; ks < 2; ks++) {
      bf16x8 af[4], bfr[4];
#pragma unroll
      for (int fm = 0; fm < 4; fm++) {
        int r = (wr << 6) + (fm << 4) + l15;
        int c = (ks << 2) + l4;
        af[fm] = *(const bf16x8*)(As + (r << 6) + ((c ^ (r & 7)) << 3));
      }
#pragma unroll
      for (int fn = 0; fn < 4; fn++) {
        int r = (wc << 6) + (fn << 4) + l15;
        int c = (ks << 2) + l4;
        bfr[fn] = *(const bf16x8*)(Bs + (r << 6) + ((c ^ (r & 7)) << 3));
      }
#pragma unroll
      for (int fm = 0; fm < 4; fm++)
#pragma unroll
        for (int fn = 0; fn < 4; fn++)
          acc[fm][fn] = __builtin_amdgcn_mfma_f32_16x16x32_bf16(af[fm], bfr[fn], acc[fm][fn], 0, 0, 0);
    }
  }

  // epilogue: lane holds D[m = 4*l4 + i][n = l15] per 16x16 fragment
#pragma unroll
  for (int fm = 0; fm < 4; fm++) {
#pragma unroll
    for (int i = 0; i < 4; i++) {
      int gr = bm + (wr << 6) + (fm << 4) + (l4 << 2) + i;
      int w_ = 0, n_ = 0, b2 = 0, l_ = 0;
      if constexpr (EPI == 0 || EPI == 1) {
        w_ = gr / 343;
        n_ = gr - w_ * 343;
      }
      if constexpr (EPI == 1) {
        b2 = w_ >> 6;
        int wrem = w_ & 63;
        int wd = wrem >> 4, wh = (wrem >> 2) & 3, ww = wrem & 3;
        int ii = n_ / 49, rem = n_ - ii * 49;
        int jj = rem / 7, kk = rem - jj * 7;
        int d = wd * 7 + ii + 3; if (d >= 28) d -= 28;
        int hh = wh * 7 + jj + 3; if (hh >= 28) hh -= 28;
        int wb = ww * 7 + kk + 3; if (wb >= 28) wb -= 28;
        l_ = (d * 28 + hh) * 28 + wb;
      }
#pragma unroll
      for (int fn = 0; fn < 4; fn++) {
        int gc = bn + (wc << 6) + (fn << 4) + l15;
        float v0 = acc[fm][fn][i];
        if constexpr (EPI == 0) {
          if (gc < 576) {
            float vb = v0 + bias[gc];
            int which = gc / 192;
            int cc3 = gc - which * 192;
            int hh2 = cc3 >> 5, dd = cc3 & 31;
            size_t off = ((size_t)(w_ * 6 + hh2) * 343 + n_) * 32 + dd;
            if (which == 0) oq[off] = f2bf(vb * 0.17677669529663687f);
            else if (which == 1) okk[off] = f2bf(vb);
            else ov[off] = f2bf(vb);
          }
        } else if constexpr (EPI == 1) {
          if (gc < 192) {
            size_t oi = ((size_t)b2 * 21952 + l_) * 192 + gc;
            of[oi] = v0 + bias[gc] + resid[oi];
          }
        } else if constexpr (EPI == 2) {
          float y = v0 + bias[gc];
          float gl = y * 0.5f * (1.0f + erff(y * 0.70710678118654752f));
          obf[(size_t)gr * 768 + gc] = f2bf(gl);
        } else {
          if (gc < 192) {
            size_t oi = (size_t)gr * 192 + gc;
            of[oi] = v0 + bias[gc] + resid[oi];
          }
        }
      }
    }
  }
}

// ---------------- attention: 1 block per (window, head), 1 thread per query row ----
__global__ __launch_bounds__(384) void attn_kernel(const unsigned short* __restrict__ q,
                                                   const unsigned short* __restrict__ k,
                                                   const unsigned short* __restrict__ v,
                                                   const float* __restrict__ rel_table,
                                                   unsigned short* __restrict__ out) {
  __shared__ __align__(16) unsigned short Kl[343 * 32];
  __shared__ __align__(16) unsigned short Vl[343 * 32];
  __shared__ float tbl[2197];
  __shared__ unsigned short mb[343];
  __shared__ unsigned char mc[343];

  int blk = blockIdx.x;
  int w_ = blk / 6, h_ = blk - w_ * 6;
  int wrem = w_ & 63;
  int wd = wrem >> 4, wh = (wrem >> 2) & 3, ww = wrem & 3;
  int t = threadIdx.x;

  const uint4* kg = (const uint4*)(k + (size_t)blk * (343 * 32));
  const uint4* vg = (const uint4*)(v + (size_t)blk * (343 * 32));
  for (int c = t; c < 1372; c += 384) {
    ((uint4*)Kl)[c] = kg[c];
    ((uint4*)Vl)[c] = vg[c];
  }
  for (int c = t; c < 2197; c += 384) tbl[c] = rel_table[c * 6 + h_];
  if (t < 343) {
    int ii = t / 49, rem = t - ii * 49;
    int jj = rem / 7, kk = rem - jj * 7;
    mb[t] = (unsigned short)(ii * 169 + jj * 13 + kk);
    int d = wd * 7 + ii, hh = wh * 7 + jj, wb = ww * 7 + kk;
    int cd = (d < 21) ? 0 : ((d < 25) ? 1 : 2);
    int ch = (hh < 21) ? 0 : ((hh < 25) ? 1 : 2);
    int cw = (wb < 21) ? 0 : ((wb < 25) ? 1 : 2);
    mc[t] = (unsigned char)(cd * 9 + ch * 3 + cw);
  }
  __syncthreads();
  if (t >= 343) return;

  float qr[32];
  {
    const unsigned int* qg = (const unsigned int*)(q + ((size_t)blk * 343 + t) * 32);
#pragma unroll
    for (int d2 = 0; d2 < 16; d2++) {
      unsigned int u = qg[d2];
      qr[2 * d2] = bflo(u);
      qr[2 * d2 + 1] = bfhi(u);
    }
  }
  int basen = mb[t] + 1098;
  int cn = mc[t];
  float o[32];
#pragma unroll
  for (int d2 = 0; d2 < 32; d2++) o[d2] = 0.f;
  float lsum = 0.f;

  for (int m = 0; m < 343; m++) {
    const unsigned int* kr = (const unsigned int*)(Kl + m * 32);
    float a0 = 0.f, a1 = 0.f, a2 = 0.f, a3 = 0.f;
#pragma unroll
    for (int d2 = 0; d2 < 16; d2 += 4) {
      unsigned int u0 = kr[d2], u1 = kr[d2 + 1], u2 = kr[d2 + 2], u3 = kr[d2 + 3];
      a0 = fmaf(qr[2 * d2], bflo(u0), a0);     a0 = fmaf(qr[2 * d2 + 1], bfhi(u0), a0);
      a1 = fmaf(qr[2 * d2 + 2], bflo(u1), a1); a1 = fmaf(qr[2 * d2 + 3], bfhi(u1), a1);
      a2 = fmaf(qr[2 * d2 + 4], bflo(u2), a2); a2 = fmaf(qr[2 * d2 + 5], bfhi(u2), a2);
      a3 = fmaf(qr[2 * d2 + 6], bflo(u3), a3); a3 = fmaf(qr[2 * d2 + 7], bfhi(u3), a3);
    }
    float s = (a0 + a1) + (a2 + a3);
    s += tbl[basen - mb[m]];
    if (cn != mc[m]) s -= 100.f;
    float p = __expf(fminf(s, 40.f));
    lsum += p;
    const unsigned int* vr = (const unsigned int*)(Vl + m * 32);
#pragma unroll
    for (int d2 = 0; d2 < 16; d2++) {
      unsigned int u = vr[d2];
      o[2 * d2] = fmaf(p, bflo(u), o[2 * d2]);
      o[2 * d2 + 1] = fmaf(p, bfhi(u), o[2 * d2 + 1]);
    }
  }
  float inv = 1.0f / lsum;
  unsigned short* orow = out + ((size_t)w_ * 343 + t) * 192 + h_ * 32;
#pragma unroll
  for (int d2 = 0; d2 < 32; d2++) orow[d2] = f2bf(o[d2] * inv);
}

// ---------------- launcher ----------------
extern "C" void kernel_launch(void* const* d_in, const int* in_sizes, int n_in,
                              void* d_out, int out_size, void* d_ws, size_t ws_size,
                              hipStream_t stream) {
  const float* x      = (const float*)d_in[0];
  const float* n1g    = (const float*)d_in[1];
  const float* n1b    = (const float*)d_in[2];
  const float* qkv_w  = (const float*)d_in[3];
  const float* qkv_b  = (const float*)d_in[4];
  const float* proj_w = (const float*)d_in[5];
  const float* proj_b = (const float*)d_in[6];
  const float* rel_t  = (const float*)d_in[7];
  const float* n2g    = (const float*)d_in[8];
  const float* n2b    = (const float*)d_in[9];
  const float* fc1_w  = (const float*)d_in[10];
  const float* fc1_b  = (const float*)d_in[11];
  const float* fc2_w  = (const float*)d_in[12];
  const float* fc2_b  = (const float*)d_in[13];

  char* ws = (char*)d_ws;
  // layout (bytes):
  // 0        WQKV  640x192 bf16   (245760)
  // 245760   WPROJ 256x192 bf16   (98304)
  // 344064   WFC1  768x192 bf16   (294912)
  // 638976   WFC2  256x768 bf16   (393216)
  // 1032192  XW    87808x192 bf16 (33718272)  [xw -> attn_out -> y2]
  // 34750464 Q,K,V each 16859136 bf16 (3x33718272); G (87808x768 bf16, 134873088) reuses this
  // 169623552 XNEW 87808x192 f32  (67436544)
  // total 237060096
  if (ws_size < 237060096ull) return;
  unsigned short* WQKV  = (unsigned short*)(ws);
  unsigned short* WPROJ = (unsigned short*)(ws + 245760);
  unsigned short* WFC1  = (unsigned short*)(ws + 344064);
  unsigned short* WFC2  = (unsigned short*)(ws + 638976);
  unsigned short* XW    = (unsigned short*)(ws + 1032192);
  unsigned short* Q_    = (unsigned short*)(ws + 34750464);
  unsigned short* K_    = Q_ + 16859136;
  unsigned short* V_    = K_ + 16859136;
  unsigned short* G_    = Q_;
  float* XNEW = (float*)(ws + 169623552);
  float* OUT = (float*)d_out;

  wconv_kernel<<<480, 256, 0, stream>>>(qkv_w, WQKV, 110592, 122880);
  wconv_kernel<<<192, 256, 0, stream>>>(proj_w, WPROJ, 36864, 49152);
  wconv_kernel<<<576, 256, 0, stream>>>(fc1_w, WFC1, 147456, 147456);
  wconv_kernel<<<768, 256, 0, stream>>>(fc2_w, WFC2, 147456, 196608);

  ln_kernel<true><<<21952, 256, 0, stream>>>(x, n1g, n1b, XW);

  gemm128<0><<<dim3(5, 686), 256, 0, stream>>>(XW, WQKV, qkv_b, 192, Q_, K_, V_, nullptr, nullptr, nullptr);

  attn_kernel<<<1536, 384, 0, stream>>>(Q_, K_, V_, rel_t, XW);

  gemm128<1><<<dim3(2, 686), 256, 0, stream>>>(XW, WPROJ, proj_b, 192, nullptr, nullptr, nullptr, nullptr, XNEW, x);

  ln_kernel<false><<<21952, 256, 0, stream>>>(XNEW, n2g, n2b, XW);

  gemm128<2><<<dim3(6, 686), 256, 0, stream>>>(XW, WFC1, fc1_b, 192, nullptr, nullptr, nullptr, G_, nullptr, nullptr);

  gemm128<3><<<dim3(2, 686), 256, 0, stream>>>(G_, WFC2, fc2_b, 768, nullptr, nullptr, nullptr, nullptr, OUT, XNEW);
}

// Round 2
// 581.684 us; speedup vs baseline: 2.2349x; 2.2349x over previous
//
#include <hip/hip_runtime.h>

#define DEV __device__ __forceinline__

typedef __bf16 bf16x8 __attribute__((ext_vector_type(8)));
typedef float f32x4 __attribute__((ext_vector_type(4)));

DEV float bflo(unsigned int u) { union { unsigned int x; float f; } c; c.x = u << 16; return c.f; }
DEV float bfhi(unsigned int u) { union { unsigned int x; float f; } c; c.x = u & 0xffff0000u; return c.f; }
DEV unsigned short f2bf(float f) {
  union { float f; unsigned int u; } c; c.f = f;
  unsigned int u = c.u;
  return (unsigned short)((u + 0x7fffu + ((u >> 16) & 1u)) >> 16);
}

// ---------------- weight convert + zero-pad (rows appended) ----------------
__global__ __launch_bounds__(256) void wconv_kernel(const float* __restrict__ src,
                                                    unsigned short* __restrict__ dst,
                                                    int real_elems, int pad_elems) {
  int i = blockIdx.x * 256 + threadIdx.x;
  if (i < pad_elems) dst[i] = (i < real_elems) ? f2bf(src[i]) : (unsigned short)0;
}

// ---------------- LayerNorm (C=192), optional roll+window gather ----------------
template <bool GATHER>
__global__ __launch_bounds__(256) void ln_kernel(const float* __restrict__ x,
                                                 const float* __restrict__ g,
                                                 const float* __restrict__ b,
                                                 unsigned short* __restrict__ out) {
  int row = (blockIdx.x << 2) + (threadIdx.x >> 6);
  int lane = threadIdx.x & 63;
  const float* xr;
  if (GATHER) {
    int w_ = row / 343, n_ = row - w_ * 343;
    int bb = w_ >> 6, wrem = w_ & 63;
    int wd = wrem >> 4, wh = (wrem >> 2) & 3, ww = wrem & 3;
    int ii = n_ / 49, rem = n_ - ii * 49;
    int jj = rem / 7, kk = rem - jj * 7;
    int d = wd * 7 + ii + 3; if (d >= 28) d -= 28;
    int hh = wh * 7 + jj + 3; if (hh >= 28) hh -= 28;
    int wb = ww * 7 + kk + 3; if (wb >= 28) wb -= 28;
    xr = x + ((size_t)bb * 21952 + (d * 28 + hh) * 28 + wb) * 192;
  } else {
    xr = x + (size_t)row * 192;
  }
  float v0 = xr[lane], v1 = xr[lane + 64], v2 = xr[lane + 128];
  float s = v0 + v1 + v2;
  float sq = v0 * v0 + v1 * v1 + v2 * v2;
#pragma unroll
  for (int o = 32; o > 0; o >>= 1) {
    s += __shfl_xor(s, o, 64);
    sq += __shfl_xor(sq, o, 64);
  }
  float mean = s * (1.0f / 192.0f);
  float var = sq * (1.0f / 192.0f) - mean * mean;
  float rstd = rsqrtf(var + 1e-5f);
  unsigned short* orow = out + (size_t)row * 192;
  orow[lane]       = f2bf((v0 - mean) * rstd * g[lane] + b[lane]);
  orow[lane + 64]  = f2bf((v1 - mean) * rstd * g[lane + 64] + b[lane + 64]);
  orow[lane + 128] = f2bf((v2 - mean) * rstd * g[lane + 128] + b[lane + 128]);
}

// ---------------- 128x128x64 bf16 MFMA GEMM, fused epilogues ----------------
// C[M][Npad] = A[M][K] @ W[Npad][K]^T ; EPI: 0=QKV scatter (V written transposed),
// 1=proj+reverse+roll+resid, 2=FC1+GELU->bf16, 3=FC2+resid->f32
template <int EPI>
__global__ __launch_bounds__(256) void gemm128(
    const unsigned short* __restrict__ A, const unsigned short* __restrict__ W,
    const float* __restrict__ bias, int K,
    unsigned short* __restrict__ oq, unsigned short* __restrict__ okk,
    unsigned short* __restrict__ ov, unsigned short* __restrict__ obf,
    float* __restrict__ of, const float* __restrict__ resid) {
  __shared__ __align__(16) unsigned short As[128 * 64];
  __shared__ __align__(16) unsigned short Bs[128 * 64];
  const int tid = threadIdx.x;
  const int lane = tid & 63;
  const int wv = tid >> 6;
  const int wr = wv >> 1, wc = wv & 1;
  const int bm = blockIdx.y << 7;
  const int bn = blockIdx.x << 7;
  const int l15 = lane & 15, l4 = lane >> 4;

  f32x4 acc[4][4];
#pragma unroll
  for (int a = 0; a < 4; a++)
#pragma unroll
    for (int b2 = 0; b2 < 4; b2++) acc[a][b2] = (f32x4){0.f, 0.f, 0.f, 0.f};

  const int kiters = K >> 6;
  for (int kt = 0; kt < kiters; kt++) {
    __syncthreads();
#pragma unroll
    for (int s = 0; s < 4; s++) {
      int qq = tid + (s << 8);
      int r = qq >> 3, cc2 = qq & 7;
      uint4 av = *(const uint4*)(A + (size_t)(bm + r) * K + (kt << 6) + (cc2 << 3));
      uint4 wvv = *(const uint4*)(W + (size_t)(bn + r) * K + (kt << 6) + (cc2 << 3));
      int so = (r << 6) + ((cc2 ^ (r & 7)) << 3);
      *(uint4*)(As + so) = av;
      *(uint4*)(Bs + so) = wvv;
    }
    __syncthreads();
#pragma unroll
    for (int ks = 0; ks < 2; ks++) {
      bf16x8 af[4], bfr[4];
#pragma unroll
      for (int fm = 0; fm < 4; fm++) {
        int r = (wr << 6) + (fm << 4) + l15;
        int c = (ks << 2) + l4;
        af[fm] = *(const bf16x8*)(As + (r << 6) + ((c ^ (r & 7)) << 3));
      }
#pragma unroll
      for (int fn = 0; fn < 4; fn++) {
        int r = (wc << 6) + (fn << 4) + l15;
        int c = (ks << 2) + l4;
        bfr[fn] = *(const bf16x8*)(Bs + (r << 6) + ((c ^ (r & 7)) << 3));
      }
#pragma unroll
      for (int fm = 0; fm < 4; fm++)
#pragma unroll
        for (int fn = 0; fn < 4; fn++)
          acc[fm][fn] = __builtin_amdgcn_mfma_f32_16x16x32_bf16(af[fm], bfr[fn], acc[fm][fn], 0, 0, 0);
    }
  }

  // epilogue: lane holds D[m = 4*l4 + i][n = l15] per 16x16 fragment
#pragma unroll
  for (int fm = 0; fm < 4; fm++) {
#pragma unroll
    for (int i = 0; i < 4; i++) {
      int gr = bm + (wr << 6) + (fm << 4) + (l4 << 2) + i;
      int w_ = 0, n_ = 0, b2 = 0, l_ = 0;
      if constexpr (EPI == 0 || EPI == 1) {
        w_ = gr / 343;
        n_ = gr - w_ * 343;
      }
      if constexpr (EPI == 1) {
        b2 = w_ >> 6;
        int wrem = w_ & 63;
        int wd = wrem >> 4, wh = (wrem >> 2) & 3, ww = wrem & 3;
        int ii = n_ / 49, rem = n_ - ii * 49;
        int jj = rem / 7, kk = rem - jj * 7;
        int d = wd * 7 + ii + 3; if (d >= 28) d -= 28;
        int hh = wh * 7 + jj + 3; if (hh >= 28) hh -= 28;
        int wb = ww * 7 + kk + 3; if (wb >= 28) wb -= 28;
        l_ = (d * 28 + hh) * 28 + wb;
      }
#pragma unroll
      for (int fn = 0; fn < 4; fn++) {
        int gc = bn + (wc << 6) + (fn << 4) + l15;
        float v0 = acc[fm][fn][i];
        if constexpr (EPI == 0) {
          if (gc < 576) {
            float vb = v0 + bias[gc];
            int which = gc / 192;
            int cc3 = gc - which * 192;
            int hh2 = cc3 >> 5, dd = cc3 & 31;
            if (which == 0) {
              size_t off = ((size_t)(w_ * 6 + hh2) * 343 + n_) * 32 + dd;
              oq[off] = f2bf(vb * 0.17677669529663687f);
            } else if (which == 1) {
              size_t off = ((size_t)(w_ * 6 + hh2) * 343 + n_) * 32 + dd;
              okk[off] = f2bf(vb);
            } else {
              // V stored transposed: VT[(w*6+h)*32 + d][0..351], pad cols stay 0
              size_t off = ((size_t)(w_ * 6 + hh2) * 32 + dd) * 352 + n_;
              ov[off] = f2bf(vb);
            }
          }
        } else if constexpr (EPI == 1) {
          if (gc < 192) {
            size_t oi = ((size_t)b2 * 21952 + l_) * 192 + gc;
            of[oi] = v0 + bias[gc] + resid[oi];
          }
        } else if constexpr (EPI == 2) {
          float y = v0 + bias[gc];
          float gl = y * 0.5f * (1.0f + erff(y * 0.70710678118654752f));
          obf[(size_t)gr * 768 + gc] = f2bf(gl);
        } else {
          if (gc < 192) {
            size_t oi = (size_t)gr * 192 + gc;
            of[oi] = v0 + bias[gc] + resid[oi];
          }
        }
      }
    }
  }
}

// ---------------- MFMA attention: 1 block per (window, head), 4 waves ----------------
// Wave owns 16-row Q tiles (tq = wave, wave+4, ...). S row-block (16x352) in registers.
__global__ __launch_bounds__(256) void attn_mfma(const unsigned short* __restrict__ q,
                                                 const unsigned short* __restrict__ k,
                                                 const unsigned short* __restrict__ vt,
                                                 const float* __restrict__ rel_table,
                                                 unsigned short* __restrict__ out) {
  __shared__ __align__(16) unsigned short Ks[352 * 40];   // K rows, stride 40 (2-way banks)
  __shared__ __align__(16) unsigned short Vt[32 * 360];   // V^T rows, stride 360
  __shared__ __align__(16) unsigned short Pb[4][16 * 40]; // per-wave P transpose buffer
  __shared__ unsigned short tbl[2200];                    // bias table, bf16
  __shared__ unsigned short mbs[344];
  __shared__ unsigned char mcs[344];

  const int blk = blockIdx.x;
  const int w_ = blk / 6, h_ = blk - w_ * 6;
  const int t = threadIdx.x;
  const int lane = t & 63, wv = t >> 6;
  const int l15 = lane & 15, l4 = lane >> 4;

  // stage K (343x32) -> Ks
  const uint4* kg = (const uint4*)(k + (size_t)blk * (343 * 32));
  for (int c = t; c < 1372; c += 256) {
    int r = c >> 2, ch = c & 3;
    *(uint4*)(Ks + r * 40 + ch * 8) = kg[c];
  }
  // stage V^T (32x352, pads already zero) -> Vt
  const uint4* vg = (const uint4*)(vt + (size_t)blk * (32 * 352));
  for (int c = t; c < 1408; c += 256) {
    int r = c / 44, ch = c - r * 44;
    *(uint4*)(Vt + r * 360 + ch * 8) = vg[c];
  }
  for (int c = t; c < 2197; c += 256) tbl[c] = f2bf(rel_table[c * 6 + h_]);
  {
    int wrem = w_ & 63;
    int wd = wrem >> 4, wh = (wrem >> 2) & 3, ww = wrem & 3;
    for (int n = t; n < 343; n += 256) {
      int ii = n / 49, rem = n - ii * 49;
      int jj = rem / 7, kk = rem - jj * 7;
      mbs[n] = (unsigned short)(ii * 169 + jj * 13 + kk);
      int d = wd * 7 + ii, hh = wh * 7 + jj, wb = ww * 7 + kk;
      int cd = (d < 21) ? 0 : ((d < 25) ? 1 : 2);
      int ch2 = (hh < 21) ? 0 : ((hh < 25) ? 1 : 2);
      int cw = (wb < 21) ? 0 : ((wb < 25) ? 1 : 2);
      mcs[n] = (unsigned char)(cd * 9 + ch2 * 3 + cw);
    }
  }
  __syncthreads();

  unsigned short* Pw = Pb[wv];

  for (int tq = wv; tq < 22; tq += 4) {
    // Q fragment: A[m=l15][k = l4*8..l4*8+7]
    int qrow = tq * 16 + l15; if (qrow > 342) qrow = 342;
    bf16x8 qf = *(const bf16x8*)(q + ((size_t)blk * 343 + qrow) * 32 + l4 * 8);

    // S = Q K^T (22 k-tiles, single MFMA each since K = HD = 32)
    f32x4 s[22];
#pragma unroll
    for (int kt = 0; kt < 22; kt++) {
      bf16x8 kf = *(const bf16x8*)(Ks + (kt * 16 + l15) * 40 + l4 * 8);
      s[kt] = __builtin_amdgcn_mfma_f32_16x16x32_bf16(qf, kf, (f32x4){0.f, 0.f, 0.f, 0.f}, 0, 0, 0);
    }

    // bias + mask + exp + rowsum. lane holds S[q=tq*16+4*l4+i][col=kt*16+l15]
    int mq[4], cq[4];
#pragma unroll
    for (int i = 0; i < 4; i++) {
      int qg = tq * 16 + 4 * l4 + i; if (qg > 342) qg = 342;
      mq[i] = mbs[qg] + 1098;
      cq[i] = mcs[qg];
    }
    float lsum[4] = {0.f, 0.f, 0.f, 0.f};
#pragma unroll
    for (int kt = 0; kt < 22; kt++) {
      int col = kt * 16 + l15;
      int colc = col > 342 ? 342 : col;
      int mcb = mbs[colc];
      int ccb = mcs[colc];
      bool cvalid = col < 343;
#pragma unroll
      for (int i = 0; i < 4; i++) {
        float sv = s[kt][i] + bflo(tbl[mq[i] - mcb]);
        if (cq[i] != ccb) sv -= 100.f;
        if (!cvalid) sv = -1e30f;
        float p = __expf(sv);
        s[kt][i] = p;
        lsum[i] += p;
      }
    }
#pragma unroll
    for (int i = 0; i < 4; i++) {
#pragma unroll
      for (int o = 1; o < 16; o <<= 1) lsum[i] += __shfl_xor(lsum[i], o, 64);
    }

    // O = P V via LDS transpose of P (32-col chunks)
    f32x4 oacc[2];
    oacc[0] = (f32x4){0.f, 0.f, 0.f, 0.f};
    oacc[1] = (f32x4){0.f, 0.f, 0.f, 0.f};
#pragma unroll
    for (int ck = 0; ck < 11; ck++) {
#pragma unroll
      for (int half = 0; half < 2; half++) {
        int kt = ck * 2 + half;
#pragma unroll
        for (int i = 0; i < 4; i++)
          Pw[(4 * l4 + i) * 40 + half * 16 + l15] = f2bf(s[kt][i]);
      }
      bf16x8 pf = *(const bf16x8*)(Pw + l15 * 40 + l4 * 8);
#pragma unroll
      for (int dt = 0; dt < 2; dt++) {
        bf16x8 vf = *(const bf16x8*)(Vt + (dt * 16 + l15) * 360 + ck * 32 + l4 * 8);
        oacc[dt] = __builtin_amdgcn_mfma_f32_16x16x32_bf16(pf, vf, oacc[dt], 0, 0, 0);
      }
    }

    // write O rows q = tq*16 + 4*l4 + i, cols h*32 + dt*16 + l15
#pragma unroll
    for (int i = 0; i < 4; i++) {
      int qg = tq * 16 + 4 * l4 + i;
      if (qg < 343) {
        float inv = 1.0f / lsum[i];
        unsigned short* orow = out + ((size_t)w_ * 343 + qg) * 192 + h_ * 32;
        orow[l15] = f2bf(oacc[0][i] * inv);
        orow[16 + l15] = f2bf(oacc[1][i] * inv);
      }
    }
  }
}

// ---------------- launcher ----------------
extern "C" void kernel_launch(void* const* d_in, const int* in_sizes, int n_in,
                              void* d_out, int out_size, void* d_ws, size_t ws_size,
                              hipStream_t stream) {
  const float* x      = (const float*)d_in[0];
  const float* n1g    = (const float*)d_in[1];
  const float* n1b    = (const float*)d_in[2];
  const float* qkv_w  = (const float*)d_in[3];
  const float* qkv_b  = (const float*)d_in[4];
  const float* proj_w = (const float*)d_in[5];
  const float* proj_b = (const float*)d_in[6];
  const float* rel_t  = (const float*)d_in[7];
  const float* n2g    = (const float*)d_in[8];
  const float* n2b    = (const float*)d_in[9];
  const float* fc1_w  = (const float*)d_in[10];
  const float* fc1_b  = (const float*)d_in[11];
  const float* fc2_w  = (const float*)d_in[12];
  const float* fc2_b  = (const float*)d_in[13];

  char* ws = (char*)d_ws;
  // layout (bytes):
  // 0         WQKV  640x192 bf16    (245760)
  // 245760    WPROJ 256x192 bf16    (98304)
  // 344064    WFC1  768x192 bf16    (294912)
  // 638976    WFC2  256x768 bf16    (393216)
  // 1032192   XW    87808x192 bf16  (33718272)   [xw -> attn_out -> y2]
  // 34750464  Q_    1536x343x32 bf16 (33718272)
  // 68468736  K_    1536x343x32 bf16 (33718272)
  // 102187008 VT    1536x32x352 bf16 (34603008)
  //   [G (87808x768 bf16 = 134873088 B) reuses 34750464..169623552]
  // 169623552 XNEW  87808x192 f32   (67436544)
  // total 237060096
  if (ws_size < 237060096ull) return;
  unsigned short* WQKV  = (unsigned short*)(ws);
  unsigned short* WPROJ = (unsigned short*)(ws + 245760);
  unsigned short* WFC1  = (unsigned short*)(ws + 344064);
  unsigned short* WFC2  = (unsigned short*)(ws + 638976);
  unsigned short* XW    = (unsigned short*)(ws + 1032192);
  unsigned short* Q_    = (unsigned short*)(ws + 34750464);
  unsigned short* K_    = (unsigned short*)(ws + 68468736);
  unsigned short* VT    = (unsigned short*)(ws + 102187008);
  unsigned short* G_    = (unsigned short*)(ws + 34750464);
  float* XNEW = (float*)(ws + 169623552);
  float* OUT = (float*)d_out;

  wconv_kernel<<<480, 256, 0, stream>>>(qkv_w, WQKV, 110592, 122880);
  wconv_kernel<<<192, 256, 0, stream>>>(proj_w, WPROJ, 36864, 49152);
  wconv_kernel<<<576, 256, 0, stream>>>(fc1_w, WFC1, 147456, 147456);
  wconv_kernel<<<768, 256, 0, stream>>>(fc2_w, WFC2, 147456, 196608);

  // V^T pad columns must be exact zeros (0 * garbage would NaN the PV MFMA)
  hipMemsetAsync(VT, 0, 34603008, stream);

  ln_kernel<true><<<21952, 256, 0, stream>>>(x, n1g, n1b, XW);

  gemm128<0><<<dim3(5, 686), 256, 0, stream>>>(XW, WQKV, qkv_b, 192, Q_, K_, VT, nullptr, nullptr, nullptr);

  attn_mfma<<<1536, 256, 0, stream>>>(Q_, K_, VT, rel_t, XW);

  gemm128<1><<<dim3(2, 686), 256, 0, stream>>>(XW, WPROJ, proj_b, 192, nullptr, nullptr, nullptr, nullptr, XNEW, x);

  ln_kernel<false><<<21952, 256, 0, stream>>>(XNEW, n2g, n2b, XW);

  gemm128<2><<<dim3(6, 686), 256, 0, stream>>>(XW, WFC1, fc1_b, 192, nullptr, nullptr, nullptr, G_, nullptr, nullptr);

  gemm128<3><<<dim3(2, 686), 256, 0, stream>>>(G_, WFC2, fc2_b, 768, nullptr, nullptr, nullptr, nullptr, OUT, XNEW);
}